// Round 2
// baseline (587.287 us; speedup 1.0000x reference)
//
#include <hip/hip_runtime.h>

#define NCLS 19
#define HW (512 * 512)
#define NB_ 16                 // batch
#define CONF_BINS (NCLS * NCLS) // 361
#define BLOCKS_PER_SAMPLE 64
#define PIX_PER_BLOCK (HW / BLOCKS_PER_SAMPLE) // 4096
#define THREADS 256

__global__ void zero_conf_kernel(unsigned int* __restrict__ conf) {
    int i = blockIdx.x * blockDim.x + threadIdx.x;
    if (i < NB_ * CONF_BINS) conf[i] = 0u;
}

__global__ __launch_bounds__(THREADS)
void conf_kernel(const float* __restrict__ x,
                 const float* __restrict__ seg,
                 unsigned int* __restrict__ conf) {
    __shared__ unsigned int lconf[CONF_BINS];
    for (int i = threadIdx.x; i < CONF_BINS; i += THREADS) lconf[i] = 0u;
    __syncthreads();

    const int b   = blockIdx.x / BLOCKS_PER_SAMPLE;
    const int blk = blockIdx.x % BLOCKS_PER_SAMPLE;
    const int p0  = blk * PIX_PER_BLOCK;

    const float* __restrict__ xb = x   + (size_t)b * NCLS * HW;
    const float* __restrict__ sb = seg + (size_t)b * NCLS * HW;

    // PIX_PER_BLOCK / (THREADS*4) = 4 iterations, 4 pixels/thread/iter
    for (int it = 0; it < PIX_PER_BLOCK / (THREADS * 4); ++it) {
        const int p = p0 + (it * THREADS + threadIdx.x) * 4;

        float4 vx = *(const float4*)(xb + p);
        float4 vs = *(const float4*)(sb + p);
        float mx[4] = {vx.x, vx.y, vx.z, vx.w};
        float ms[4] = {vs.x, vs.y, vs.z, vs.w};
        int   ax[4] = {0, 0, 0, 0};
        int   as_[4] = {0, 0, 0, 0};

        #pragma unroll
        for (int c = 1; c < NCLS; ++c) {
            float4 cx = *(const float4*)(xb + (size_t)c * HW + p);
            float4 cs = *(const float4*)(sb + (size_t)c * HW + p);
            float fx[4] = {cx.x, cx.y, cx.z, cx.w};
            float fs[4] = {cs.x, cs.y, cs.z, cs.w};
            #pragma unroll
            for (int k = 0; k < 4; ++k) {
                if (fx[k] > mx[k]) { mx[k] = fx[k]; ax[k] = c; }
                if (fs[k] > ms[k]) { ms[k] = fs[k]; as_[k] = c; }
            }
        }
        #pragma unroll
        for (int k = 0; k < 4; ++k) {
            atomicAdd(&lconf[as_[k] * NCLS + ax[k]], 1u);
        }
    }
    __syncthreads();

    unsigned int* __restrict__ gc = conf + b * CONF_BINS;
    for (int i = threadIdx.x; i < CONF_BINS; i += THREADS) {
        unsigned int v = lconf[i];
        if (v) atomicAdd(&gc[i], v);
    }
}

__global__ __launch_bounds__(512)
void miou_kernel(const unsigned int* __restrict__ conf, float* __restrict__ out) {
    __shared__ float sdata[512];
    const int t = threadIdx.x;
    float iou = 0.0f;
    if (t < NB_ * NCLS) {
        const int b = t / NCLS;
        const int c = t % NCLS;
        const unsigned int* __restrict__ cb = conf + b * CONF_BINS;
        float diag = (float)cb[c * NCLS + c];
        float row = 0.0f, col = 0.0f;
        #pragma unroll
        for (int j = 0; j < NCLS; ++j) {
            row += (float)cb[c * NCLS + j];
            col += (float)cb[j * NCLS + c];
        }
        iou = diag / (row + col - diag + 1e-10f);
    }
    sdata[t] = iou;
    __syncthreads();
    #pragma unroll
    for (int s = 256; s > 0; s >>= 1) {
        if (t < s) sdata[t] += sdata[t + s];
        __syncthreads();
    }
    if (t == 0) out[0] = sdata[0] / (float)(NB_ * NCLS);
}

extern "C" void kernel_launch(void* const* d_in, const int* in_sizes, int n_in,
                              void* d_out, int out_size, void* d_ws, size_t ws_size,
                              hipStream_t stream) {
    const float* x   = (const float*)d_in[0];
    const float* seg = (const float*)d_in[1];
    float* out = (float*)d_out;
    unsigned int* conf = (unsigned int*)d_ws; // 16*361*4 = 23104 B

    zero_conf_kernel<<<(NB_ * CONF_BINS + 255) / 256, 256, 0, stream>>>(conf);
    conf_kernel<<<NB_ * BLOCKS_PER_SAMPLE, THREADS, 0, stream>>>(x, seg, conf);
    miou_kernel<<<1, 512, 0, stream>>>(conf, out);
}